// Round 3
// baseline (237.564 us; speedup 1.0000x reference)
//
#include <hip/hip_runtime.h>

// Problem geometry (fixed by the reference):
//   x: (16, 480, 64, 64) fp32;  fields: pattern {1,1,2,2,4,4,8,8} x16 groups
//   N_FIELDS=128, C_TOTAL=480, plane = 64*64 = 4096 floats (16 KB, contiguous)
#define NB      16
#define NC      480
#define NF      128
#define HW      4096
#define PLANES  (NB * NC)      // 7680
#define EPS     1e-6f

// ---------------------------------------------------------------------------
// Kernel 1: per-(batch,channel) sum of squares over the 64x64 plane.
// One block handles TWO planes; 256 threads x 8 float4 = 8192 floats.
// ---------------------------------------------------------------------------
__global__ __launch_bounds__(256) void k_sumsq(const float* __restrict__ x,
                                               float* __restrict__ sq) {
    const int pbase = blockIdx.x * 2;     // first of two planes
    const int t = threadIdx.x;

#pragma unroll
    for (int p = 0; p < 2; ++p) {
        const float4* xp = reinterpret_cast<const float4*>(x) +
                           (size_t)(pbase + p) * (HW / 4);
        float s = 0.f;
#pragma unroll
        for (int i = 0; i < 4; ++i) {
            float4 v = xp[t + i * 256];
            s = fmaf(v.x, v.x, s);
            s = fmaf(v.y, v.y, s);
            s = fmaf(v.z, v.z, s);
            s = fmaf(v.w, v.w, s);
        }
#pragma unroll
        for (int off = 32; off > 0; off >>= 1) s += __shfl_down(s, off, 64);

        __shared__ float partial[4];
        if ((t & 63) == 0) partial[t >> 6] = s;
        __syncthreads();
        if (t == 0) sq[pbase + p] = partial[0] + partial[1] + partial[2] + partial[3];
        if (p == 0) __syncthreads();   // protect partial[] reuse
    }
}

// ---------------------------------------------------------------------------
// Kernel 2: tiny. Per batch: segment-sum sq over each field, sqrt -> gx,
// mean over the 128 fields, nx = gx/(mean+eps), then expand to per-channel
//   ab[b][c] = { 1 + gamma[f(c)] * nx[b][f(c)],  beta[f(c)] }
// (algebraic fusion: g*(x*nx) + b + x == x*a + b)
// 16 blocks x 128 threads (one thread per field).
// ---------------------------------------------------------------------------
__global__ __launch_bounds__(128) void k_scale(const float* __restrict__ sq,
                                               const float* __restrict__ gamma,
                                               const float* __restrict__ beta,
                                               float2* __restrict__ ab) {
    const int b = blockIdx.x;   // 0..15
    const int f = threadIdx.x;  // 0..127

    // field f: group g = f>>3, slot k = f&7; channel start = g*30 + off[k]
    const int offs[8] = {0, 1, 2, 4, 6, 10, 14, 22};
    const int szs[8]  = {1, 1, 2, 2, 4, 4, 8, 8};
    const int k = f & 7, g = f >> 3;
    const int start = g * 30 + offs[k];
    const int sz = szs[k];

    float s = 0.f;
    for (int i = 0; i < sz; ++i) s += sq[b * NC + start + i];
    const float gx = sqrtf(s);

    // mean over 128 fields (2 waves)
    float m = gx;
#pragma unroll
    for (int off = 32; off > 0; off >>= 1) m += __shfl_down(m, off, 64);
    __shared__ float wsum[2];
    if ((f & 63) == 0) wsum[f >> 6] = m;
    __syncthreads();
    const float mean = (wsum[0] + wsum[1]) * (1.0f / (float)NF);

    const float nx = gx / (mean + EPS);
    const float2 v = make_float2(1.0f + gamma[f] * nx, beta[f]);
    for (int i = 0; i < sz; ++i) ab[b * NC + start + i] = v;
}

// ---------------------------------------------------------------------------
// Kernel 3: out = x * a[b][c] + beta[b][c]. Two planes per block, float4 I/O.
// ---------------------------------------------------------------------------
__global__ __launch_bounds__(256) void k_apply(const float* __restrict__ x,
                                               const float2* __restrict__ ab,
                                               float* __restrict__ out) {
    const int pbase = blockIdx.x * 2;
    const int t = threadIdx.x;

#pragma unroll
    for (int p = 0; p < 2; ++p) {
        const int plane = pbase + p;
        const float2 v = ab[plane];          // uniform per plane -> broadcast
        const float a = v.x, be = v.y;

        const float4* xp = reinterpret_cast<const float4*>(x)  + (size_t)plane * (HW / 4);
        float4*       op = reinterpret_cast<float4*>(out)      + (size_t)plane * (HW / 4);

#pragma unroll
        for (int i = 0; i < 4; ++i) {
            float4 u = xp[t + i * 256];
            float4 r;
            r.x = fmaf(u.x, a, be);
            r.y = fmaf(u.y, a, be);
            r.z = fmaf(u.z, a, be);
            r.w = fmaf(u.w, a, be);
            op[t + i * 256] = r;
        }
    }
}

// ---------------------------------------------------------------------------
extern "C" void kernel_launch(void* const* d_in, const int* in_sizes, int n_in,
                              void* d_out, int out_size, void* d_ws, size_t ws_size,
                              hipStream_t stream) {
    const float* x     = (const float*)d_in[0];
    const float* gamma = (const float*)d_in[1];
    const float* beta  = (const float*)d_in[2];
    float* out = (float*)d_out;

    // workspace layout: sq[7680] | ab[7680] float2  (~92 KB)
    float*  sq = (float*)d_ws;
    float2* ab = (float2*)(sq + PLANES);

    k_sumsq<<<PLANES / 2, 256, 0, stream>>>(x, sq);
    k_scale<<<NB, NF, 0, stream>>>(sq, gamma, beta, ab);
    k_apply<<<PLANES / 2, 256, 0, stream>>>(x, ab, out);
}

// Round 5
// 236.628 us; speedup vs baseline: 1.0040x; 1.0040x over previous
//
#include <hip/hip_runtime.h>

// Problem geometry (fixed by the reference):
//   x: (16, 480, 64, 64) fp32;  fields: pattern {1,1,2,2,4,4,8,8} x16 groups
//   N_FIELDS=128, C_TOTAL=480, plane = 64*64 = 4096 floats (16 KB, contiguous)
#define NB      16
#define NC      480
#define NF      128
#define HW      4096
#define PLANES  (NB * NC)      // 7680
#define EPS     1e-6f

// ---------------------------------------------------------------------------
// Kernel 1: per-(batch,channel) sum of squares over the 64x64 plane.
// One block handles TWO planes; 256 threads x 8 float4 = 8192 floats.
// ---------------------------------------------------------------------------
__global__ __launch_bounds__(256) void k_sumsq(const float* __restrict__ x,
                                               float* __restrict__ sq) {
    const int pbase = blockIdx.x * 2;     // first of two planes
    const int t = threadIdx.x;

#pragma unroll
    for (int p = 0; p < 2; ++p) {
        const float4* xp = reinterpret_cast<const float4*>(x) +
                           (size_t)(pbase + p) * (HW / 4);
        float s = 0.f;
#pragma unroll
        for (int i = 0; i < 4; ++i) {
            float4 v = xp[t + i * 256];
            s = fmaf(v.x, v.x, s);
            s = fmaf(v.y, v.y, s);
            s = fmaf(v.z, v.z, s);
            s = fmaf(v.w, v.w, s);
        }
#pragma unroll
        for (int off = 32; off > 0; off >>= 1) s += __shfl_down(s, off, 64);

        __shared__ float partial[4];
        if ((t & 63) == 0) partial[t >> 6] = s;
        __syncthreads();
        if (t == 0) sq[pbase + p] = partial[0] + partial[1] + partial[2] + partial[3];
        if (p == 0) __syncthreads();   // protect partial[] reuse
    }
}

// ---------------------------------------------------------------------------
// Kernel 2 (fused): per-block prologue recomputes the per-batch field stats
// from sq (1.9 KB, L2-hot — redundant across blocks but ~free), then streams
//   out = x * a[f(c)] + beta[f(c)]     where a = 1 + gamma*nx
// 4 planes per block (480 % 4 == 0 so a block never straddles batches).
// ---------------------------------------------------------------------------
__global__ __launch_bounds__(256) void k_apply(const float* __restrict__ x,
                                               const float* __restrict__ sq,
                                               const float* __restrict__ gamma,
                                               const float* __restrict__ beta,
                                               float* __restrict__ out) {
    const int pbase = blockIdx.x * 4;
    const int b = pbase / NC;            // batch (uniform per block)
    const int t = threadIdx.x;

    __shared__ float af[NF];
    __shared__ float bf[NF];
    __shared__ float wsum[4];

    // --- per-field gx (threads 0..127; one field each) ---
    float gx = 0.f;
    if (t < NF) {
        const int offs[8] = {0, 1, 2, 4, 6, 10, 14, 22};
        const int szs[8]  = {1, 1, 2, 2, 4, 4, 8, 8};
        const int k = t & 7, g = t >> 3;
        const int start = b * NC + g * 30 + offs[k];
        float s = 0.f;
        for (int i = 0; i < szs[k]; ++i) s += sq[start + i];
        gx = sqrtf(s);
    }
    // mean over the 128 fields (waves 2,3 contribute zeros)
    float m = gx;
#pragma unroll
    for (int off = 32; off > 0; off >>= 1) m += __shfl_down(m, off, 64);
    if ((t & 63) == 0) wsum[t >> 6] = m;
    __syncthreads();
    const float mean = (wsum[0] + wsum[1]) * (1.0f / (float)NF);
    if (t < NF) {
        const float nx = gx / (mean + EPS);
        af[t] = 1.0f + gamma[t] * nx;
        bf[t] = beta[t];
    }
    __syncthreads();

    // --- streaming apply over this block's 4 planes ---
#pragma unroll
    for (int p = 0; p < 4; ++p) {
        const int plane = pbase + p;
        const int c = plane - b * NC;          // channel 0..479
        const int g = c / 30;
        const int r = c - g * 30;
        // slot within group from cumulative sizes {0,1,2,4,6,10,14,22,30}
        const int k = (r >= 22) ? 7 : (r >= 14) ? 6 : (r >= 10) ? 5 :
                      (r >= 6)  ? 4 : (r >= 4)  ? 3 : (r >= 2)  ? 2 : r;
        const int f = g * 8 + k;
        const float a  = af[f];                // uniform per plane -> broadcast
        const float be = bf[f];

        const float4* xp = reinterpret_cast<const float4*>(x)  + (size_t)plane * (HW / 4);
        float4*       op = reinterpret_cast<float4*>(out)      + (size_t)plane * (HW / 4);

#pragma unroll
        for (int i = 0; i < 4; ++i) {
            float4 u = xp[t + i * 256];
            float4 w;
            w.x = fmaf(u.x, a, be);
            w.y = fmaf(u.y, a, be);
            w.z = fmaf(u.z, a, be);
            w.w = fmaf(u.w, a, be);
            op[t + i * 256] = w;
        }
    }
}

// ---------------------------------------------------------------------------
extern "C" void kernel_launch(void* const* d_in, const int* in_sizes, int n_in,
                              void* d_out, int out_size, void* d_ws, size_t ws_size,
                              hipStream_t stream) {
    const float* x     = (const float*)d_in[0];
    const float* gamma = (const float*)d_in[1];
    const float* beta  = (const float*)d_in[2];
    float* out = (float*)d_out;

    float* sq = (float*)d_ws;                 // sq[7680] (~30 KB)

    k_sumsq<<<PLANES / 2, 256, 0, stream>>>(x, sq);
    k_apply<<<PLANES / 4, 256, 0, stream>>>(x, sq, gamma, beta, out);
}